// Round 3
// 578.547 us; speedup vs baseline: 1.3771x; 1.3771x over previous
//
#include <hip/hip_runtime.h>
#include <hip/hip_bf16.h>

#define NN 50000
#define DD 128
#define DEF 32
#define EE 500000
#define NET 5
#define KP 832        // padded K (805 real: 5*128 H | 5*32 EF | 5 mask/bias)
#define CHUNKS 196    // ceil(50000/256)
#define NB 196        // buckets per etype (dst >> 8), 256 nodes each
#define BCHUNK 4096   // edges per binning block
#define STAGE 4096    // k_place2 LDS staging entries (slow-path beyond)

typedef unsigned short u16;
typedef unsigned int u32;
using short8 = __attribute__((ext_vector_type(8))) short;
using f32x4  = __attribute__((ext_vector_type(4))) float;

__device__ __forceinline__ u16 f2bf(float f){
  union { float f; u32 u; } v; v.f = f;
  u32 r = v.u + 0x7FFFu + ((v.u >> 16) & 1u);
  return (u16)(r >> 16);
}

// ---------------- fp32 -> bf16 cast of op_feats ----------------
__global__ void k_cast(const float* __restrict__ x, u16* __restrict__ y){
  int i = blockIdx.x*256 + threadIdx.x;     // grid covers NN*DD/4 exactly
  float4 v = ((const float4*)x)[i];
  ushort4 o; o.x=f2bf(v.x); o.y=f2bf(v.y); o.z=f2bf(v.z); o.w=f2bf(v.w);
  ((ushort4*)y)[i] = o;
}

// ---------------- pass 0: exact per-bucket counts (LDS hist -> 980 global atomics) --------
__global__ __launch_bounds__(256) void k_bcnt(
    const int* d0,const int* d1,const int* d2,const int* d3,const int* d4,
    int* __restrict__ bcnt)
{
  int et = blockIdx.y;
  const int* dp = et==0?d0:et==1?d1:et==2?d2:et==3?d3:d4;
  __shared__ int h[256];
  int tid = threadIdx.x;
  h[tid] = 0;
  __syncthreads();
  int e0 = blockIdx.x * BCHUNK;
  #pragma unroll
  for (int k = 0; k < 16; k++){
    int e = e0 + k*256 + tid;
    if (e < EE) atomicAdd(&h[dp[e] >> 8], 1);
  }
  __syncthreads();
  if (h[tid]) atomicAdd(&bcnt[et*256 + tid], h[tid]);
}

// ---------------- pass 0b: exclusive scan of bucket counts -> exact bases + cursors -------
__global__ void k_bscan(const int* __restrict__ bcnt, int* __restrict__ bB, int* __restrict__ bC){
  __shared__ int sc[256];
  int tid = threadIdx.x;
  for (int et = 0; et < NET; et++){
    int x = bcnt[et*256 + tid];
    sc[tid] = x;
    __syncthreads();
    #pragma unroll
    for (int d = 1; d < 256; d <<= 1){
      int y = (tid >= d) ? sc[tid - d] : 0;
      __syncthreads();
      sc[tid] += y;
      __syncthreads();
    }
    int excl = sc[tid] - x;
    bB[et*256 + tid] = excl;
    bC[et*256 + tid] = excl;
    __syncthreads();      // before next etype reuses sc
  }
}

// ---------------- pass 1: bin edges by dst>>8 into EXACT bucket segments ----------------
// recL.x = src(16b) | dst_low(8b)<<16 | bucket(8b)<<24 ; recL.y = edge id
// global record: bktS[g] = src (u16), bktI[g] = dst_low<<24 | edge_id(24b)
__global__ __launch_bounds__(256) void k_bin2(
    const int* d0,const int* d1,const int* d2,const int* d3,const int* d4,
    const int* s0,const int* s1,const int* s2,const int* s3,const int* s4,
    int* __restrict__ bC, u16* __restrict__ bktS, u32* __restrict__ bktI)
{
  int et = blockIdx.y;
  const int* dp = et==0?d0:et==1?d1:et==2?d2:et==3?d3:d4;
  const int* sp = et==0?s0:et==1?s1:et==2?s2:et==3?s3:s4;
  __shared__ int cntL[256];
  __shared__ int offL[256];
  __shared__ int cnt2[256];
  __shared__ int baseG[256];
  __shared__ int2 recL[BCHUNK];     // 32 KB
  int tid = threadIdx.x;
  cntL[tid] = 0; cnt2[tid] = 0;
  __syncthreads();
  int e0 = blockIdx.x * BCHUNK;
  int dv[16], sv[16];
  #pragma unroll
  for (int k = 0; k < 16; k++){
    int e = e0 + k*256 + tid;
    if (e < EE){
      dv[k] = dp[e]; sv[k] = sp[e];
      atomicAdd(&cntL[dv[k] >> 8], 1);
    } else dv[k] = -1;
  }
  __syncthreads();
  // Hillis-Steele inclusive scan of cntL -> offL
  int x = cntL[tid];
  offL[tid] = x;
  __syncthreads();
  #pragma unroll
  for (int d = 1; d < 256; d <<= 1){
    int y = (tid >= d) ? offL[tid - d] : 0;
    __syncthreads();
    offL[tid] += y;
    __syncthreads();
  }
  int excl = offL[tid] - x;
  __syncthreads();
  offL[tid] = excl;                 // exclusive prefix
  if (x > 0) baseG[tid] = atomicAdd(&bC[et*256 + tid], x);  // exact global slot range
  __syncthreads();
  int total = offL[255] + cntL[255];
  // place records bucket-sorted into LDS
  #pragma unroll
  for (int k = 0; k < 16; k++){
    if (dv[k] >= 0){
      int b = dv[k] >> 8;
      int r = atomicAdd(&cnt2[b], 1);
      recL[offL[b] + r] = make_int2((sv[k] & 0xFFFF) | ((dv[k] & 255) << 16) | (b << 24),
                                    e0 + k*256 + tid);
    }
  }
  __syncthreads();
  // coalesced write-out: piecewise-contiguous runs, NO drop guard needed (exact bases)
  for (int j = tid; j < total; j += 256){
    int2 rc = recL[j];
    int b = (rc.x >> 24) & 255;
    int g = baseG[b] + (j - offL[b]);
    bktS[(size_t)et*EE + g] = (u16)(rc.x & 0xFFFF);
    bktI[(size_t)et*EE + g] = ((u32)((rc.x >> 16) & 255) << 24) | (u32)rc.y;
  }
}

// ---------------- pass 2a: per-bucket degree count ----------------
__global__ void k_deg2(const int* __restrict__ bcnt, const int* __restrict__ bB,
                       const u32* __restrict__ bktI, int* __restrict__ deg){
  int et = blockIdx.y, b = blockIdx.x, tid = threadIdx.x;
  __shared__ int c[256];
  c[tid] = 0;
  __syncthreads();
  int cnt  = bcnt[et*256 + b];
  int base = bB[et*256 + b];
  const u32* p = bktI + (size_t)et*EE + base;
  for (int j = tid; j < cnt; j += 256) atomicAdd(&c[p[j] >> 24], 1);
  __syncthreads();
  int node = b*256 + tid;
  if (node < NN) deg[et*NN + node] = c[tid];
}

// ---------------- CSR prefix ----------------
__global__ void k_chunksum(const int* __restrict__ deg, int* __restrict__ cs){
  int et = blockIdx.y;
  int i = blockIdx.x*256 + threadIdx.x;
  int x = (i < NN) ? deg[et*NN + i] : 0;
  #pragma unroll
  for (int d = 32; d >= 1; d >>= 1) x += __shfl_down(x, d, 64);
  __shared__ int ws4[4];
  int lane = threadIdx.x & 63, w = threadIdx.x >> 6;
  if (lane == 0) ws4[w] = x;
  __syncthreads();
  if (threadIdx.x == 0) cs[et*CHUNKS + blockIdx.x] = ws4[0]+ws4[1]+ws4[2]+ws4[3];
}

__global__ void k_scanchunks(int* cs){
  int et = blockIdx.x;
  int lane = threadIdx.x;   // block = 64
  int run = 0;
  for (int c0 = 0; c0 < CHUNKS; c0 += 64){
    int i = c0 + lane;
    int x = (i < CHUNKS) ? cs[et*CHUNKS + i] : 0;
    int own = x;
    #pragma unroll
    for (int d = 1; d < 64; d <<= 1){ int y = __shfl_up(x, d, 64); if (lane >= d) x += y; }
    int tot = __shfl(x, 63, 64);
    if (i < CHUNKS) cs[et*CHUNKS + i] = run + x - own;
    run += tot;
  }
}

__global__ void k_localscan(const int* __restrict__ deg, const int* __restrict__ cs,
                            int* __restrict__ cur){
  int et = blockIdx.y;
  int i = blockIdx.x*256 + threadIdx.x;
  int lane = threadIdx.x & 63, w = threadIdx.x >> 6;
  int x = (i < NN) ? deg[et*NN + i] : 0;
  int own = x;
  #pragma unroll
  for (int d = 1; d < 64; d <<= 1){ int y = __shfl_up(x, d, 64); if (lane >= d) x += y; }
  __shared__ int ws4[4];
  if (lane == 63) ws4[w] = x;
  __syncthreads();
  int add = cs[et*CHUNKS + blockIdx.x];
  for (int k = 0; k < w; k++) add += ws4[k];
  if (i < NN){ cur[et*NN+i] = x - own + add; }   // exclusive prefix (never mutated)
}

// ---------------- pass 2b: place bucket records into CSR, coalesced, any-size safe -------
__global__ __launch_bounds__(256) void k_place2(
    const int* __restrict__ bcnt, const int* __restrict__ bB,
    const u16* __restrict__ bktS, const u32* __restrict__ bktI,
    const int* __restrict__ cur, u16* __restrict__ elS, u32* __restrict__ elI)
{
  int et = blockIdx.y, b = blockIdx.x, tid = threadIdx.x;
  __shared__ int curL[256];
  __shared__ int c2[256];
  __shared__ u16 oS[STAGE];         // 8 KB
  __shared__ u32 oI[STAGE];         // 16 KB
  int node = b*256 + tid;
  curL[tid] = (node < NN) ? cur[et*NN + node] : 0;
  c2[tid] = 0;
  __syncthreads();
  int cnt  = bcnt[et*256 + b];
  int base = bB[et*256 + b];
  int csr0 = curL[0];
  const u16* pS = bktS + (size_t)et*EE + base;
  const u32* pI = bktI + (size_t)et*EE + base;
  for (int j = tid; j < cnt; j += 256){
    u32 v = pI[j];
    u16 s = pS[j];
    int low = v >> 24;
    u32 id  = v & 0xFFFFFFu;
    int r = atomicAdd(&c2[low], 1);
    int pos = curL[low] + r - csr0;
    if (pos < STAGE){ oS[pos] = s; oI[pos] = id; }
    else { elS[(size_t)et*EE + csr0 + pos] = s; elI[(size_t)et*EE + csr0 + pos] = id; }
  }
  __syncthreads();
  int lim = cnt < STAGE ? cnt : STAGE;
  for (int j = tid; j < lim; j += 256){
    elS[(size_t)et*EE + csr0 + j] = oS[j];
    elI[(size_t)et*EE + csr0 + j] = oI[j];
  }
}

// ------------- per-(etype,node) mean gather (bf16 rows) → bf16 A row slice -------------
__global__ __launch_bounds__(256) void k_gather(
    const u16* __restrict__ opb,
    const float* e0,const float* e1,const float* e2,const float* e3,const float* e4,
    const int* __restrict__ cur, const int* __restrict__ deg,
    const u16* __restrict__ elS, const u32* __restrict__ elI, u16* __restrict__ A)
{
  int et = blockIdx.y;
  const float* efp = et==0?e0:et==1?e1:et==2?e2:et==3?e3:e4;
  int tid = threadIdx.x;
  int lane = tid & 63, w = tid >> 6;
  int v = blockIdx.x*4 + w;               // grid.x = NN/4 -> v < NN exactly
  int dg   = deg[et*NN + v];
  int base = cur[et*NN + v];              // exclusive prefix
  const u16* pS = elS + (size_t)et*EE + base;
  const u32* pI = elI + (size_t)et*EE + base;
  int laneh = lane & 31;
  int hi = lane >> 5;                     // 0 for lanes 0-31, 1 for 32-63
  float h0 = 0.f, h1 = 0.f, efa = 0.f;
  for (int i0 = 0; i0 < dg; i0 += 16){
    // phase 1: coalesced record loads (16 records replicated 4x across wave)
    int li  = i0 + (lane & 15);
    int lic = li < dg ? li : dg - 1;
    int srcv = pS[lic];
    int idv  = (int)pI[lic];
    int sL[16], eL[8];
    #pragma unroll
    for (int t = 0; t < 16; t++) sL[t] = __shfl(srcv, t, 16);
    #pragma unroll
    for (int p = 0; p < 8; p++)  eL[p] = __shfl(idv, 2*p + hi, 16);
    // phase 2: 16 independent row loads (4B/lane, 256B/row coalesced)
    u32 rv[16];
    #pragma unroll
    for (int t = 0; t < 16; t++)
      rv[t] = *((const u32*)(opb + (size_t)sL[t]*DD) + lane);
    // phase 3: 8 ef loads, all 64 lanes busy (low half: even t, high half: odd t)
    float fv[8];
    #pragma unroll
    for (int p = 0; p < 8; p++)
      fv[p] = __builtin_nontemporal_load(&efp[(size_t)eL[p]*DEF + laneh]);
    // phase 4: reduce
    #pragma unroll
    for (int t = 0; t < 16; t++){
      float wt = (i0 + t < dg) ? 1.f : 0.f;
      union {u32 u; float f;} a, b;
      a.u = rv[t] << 16; b.u = rv[t] & 0xFFFF0000u;
      h0 += a.f * wt; h1 += b.f * wt;
    }
    #pragma unroll
    for (int p = 0; p < 8; p++){
      float wt = (i0 + 2*p + hi < dg) ? 1.f : 0.f;
      efa += fv[p] * wt;
    }
  }
  efa += __shfl(efa, lane ^ 32, 64);      // combine even/odd halves
  float sc = dg > 0 ? 1.0f/(float)dg : 0.0f;
  u32 pk = (u32)f2bf(h0*sc) | ((u32)f2bf(h1*sc) << 16);
  *(u32*)(A + (size_t)v*KP + et*DD + 2*lane) = pk;
  if (lane < DEF) A[(size_t)v*KP + 640 + et*DEF + lane] = f2bf(efa*sc);
  if (lane == 0)  A[(size_t)v*KP + 800 + et] = dg > 0 ? (u16)0x3F80 : (u16)0;
  // NOTE: A cols 805..831 are never written — k_gemm masks them during staging.
}

// ------------- build Bt[j][k] (bf16, transposed, pad rows zeroed) -------------
__global__ void k_convB(const float* W0,const float* W1,const float* W2,const float* W3,const float* W4,
                        const float* b0,const float* b1,const float* b2,const float* b3,const float* b4,
                        u16* __restrict__ Bt){
  int id = blockIdx.x*256 + threadIdx.x;
  if (id >= DD*KP) return;
  int j = id / KP, k = id - j*KP;
  const float* Ws[NET] = {W0,W1,W2,W3,W4};
  const float* bs[NET] = {b0,b1,b2,b3,b4};
  float val = 0.f;
  if (k < 640)      { int et = k >> 7, r = k & 127; val = Ws[et][r*DD + j]; }
  else if (k < 800) { int q = k - 640; int et = q >> 5, r = q & 31; val = Ws[et][(DD + r)*DD + j]; }
  else if (k < 805) { val = bs[k - 800][j]; }
  Bt[(size_t)j*KP + k] = f2bf(val);
}

// ------------- fused GEMM + /5 + residual + ReLU (128-row tiles) -------------
__global__ __launch_bounds__(256) void k_gemm(const u16* __restrict__ A, const u16* __restrict__ Bt,
                                              const float* __restrict__ opf, float* __restrict__ out){
  __shared__ __align__(16) u16 As[128][40];   // +8 pad breaks power-of-2 stride
  __shared__ __align__(16) u16 Bs[128][40];
  int tid = threadIdx.x, lane = tid & 63, w = tid >> 6;
  int m0 = blockIdx.x * 128;
  f32x4 acc[2][8];
  #pragma unroll
  for (int mh = 0; mh < 2; mh++)
    #pragma unroll
    for (int nt = 0; nt < 8; nt++) acc[mh][nt] = (f32x4){0.f,0.f,0.f,0.f};

  for (int kt = 0; kt < 26; kt++){
    int k0 = kt * 32;
    #pragma unroll
    for (int i = 0; i < 2; i++){    // stage A(128x32) + B(128x32), 2 x 16B each per thread
      int idx = tid + i*256, r = idx >> 2, c = idx & 3;
      int row = m0 + r;
      int cb = k0 + c*8;            // absolute A column of this uint4
      uint4 va = {0u,0u,0u,0u};
      if (row < NN) va = *(const uint4*)(A + (size_t)row*KP + cb);
      // mask pad columns 805..831 (A pads are don't-care bytes; bkt aliases A head)
      if (cb >= 808)      { va.x = va.y = va.z = va.w = 0u; }
      else if (cb == 800) { va.z &= 0x0000FFFFu; va.w = 0u; }  // keep cols 800..804
      *(uint4*)(&As[r][c*8]) = va;
      uint4 vb = *(const uint4*)(Bt + (size_t)r*KP + cb);
      *(uint4*)(&Bs[r][c*8]) = vb;
    }
    __syncthreads();
    short8 af0 = *(const short8*)(&As[w*32      + (lane & 15)][(lane >> 4)*8]);
    short8 af1 = *(const short8*)(&As[w*32 + 16 + (lane & 15)][(lane >> 4)*8]);
    #pragma unroll
    for (int nt = 0; nt < 8; nt++){
      short8 bf = *(const short8*)(&Bs[nt*16 + (lane & 15)][(lane >> 4)*8]);
      acc[0][nt] = __builtin_amdgcn_mfma_f32_16x16x32_bf16(af0, bf, acc[0][nt], 0, 0, 0);
      acc[1][nt] = __builtin_amdgcn_mfma_f32_16x16x32_bf16(af1, bf, acc[1][nt], 0, 0, 0);
    }
    __syncthreads();
  }
  int col = lane & 15, rq = lane >> 4;
  #pragma unroll
  for (int mh = 0; mh < 2; mh++){
    #pragma unroll
    for (int nt = 0; nt < 8; nt++){
      #pragma unroll
      for (int r = 0; r < 4; r++){
        int v = m0 + w*32 + mh*16 + rq*4 + r;
        int j = nt*16 + col;
        if (v < NN){
          float x = opf[(size_t)v*DD + j] + acc[mh][nt][r] * 0.2f;
          out[(size_t)v*DD + j] = x > 0.f ? x : 0.f;
        }
      }
    }
  }
}

extern "C" void kernel_launch(void* const* d_in, const int* in_sizes, int n_in,
                              void* d_out, int out_size, void* d_ws, size_t ws_size,
                              hipStream_t stream){
  const float* opf = (const float*)d_in[0];
  const float* ef[5]; const float* W[5]; const float* bb[5]; const int* sr[5]; const int* ds[5];
  for (int t = 0; t < 5; t++){
    ef[t] = (const float*)d_in[1 + 5*t + 0];
    W [t] = (const float*)d_in[1 + 5*t + 1];
    bb[t] = (const float*)d_in[1 + 5*t + 2];
    sr[t] = (const int*)  d_in[1 + 5*t + 3];
    ds[t] = (const int*)  d_in[1 + 5*t + 4];
  }
  char* ws = (char*)d_ws;
  int*  deg  = (int*) (ws);                     //  1,000,000 B
  int*  cur  = (int*) (ws +  1000000);          //  1,000,000 B
  int*  cs   = (int*) (ws +  2000000);          //      3,920 B
  int*  bcnt = (int*) (ws +  2004992);          //      5,120 B (NET*256)
  int*  bB   = (int*) (ws +  2010112);          //      5,120 B
  int*  bC   = (int*) (ws +  2015232);          //      5,120 B
  u16*  Bt   = (u16*) (ws +  2020352);          //    212,992 B
  u16*  opb  = (u16*) (ws +  2233344);          // 12,800,000 B
  u16*  elS  = (u16*) (ws + 15033344);          //  5,000,000 B
  u32*  elI  = (u32*) (ws + 20033344);          // 10,000,000 B
  u16*  A    = (u16*) (ws + 30033344);          // 83,200,000 B -> total 113,233,344 B
  // bucket buffers alias A's head (dead before k_gather rewrites A; pads masked in k_gemm)
  u16*  bktS = (u16*) (ws + 30033344);          //  5,000,000 B
  u32*  bktI = (u32*) (ws + 35033344);          // 10,000,000 B

  hipMemsetAsync(bcnt, 0, NET*256*sizeof(int), stream);
  dim3 bE((EE + BCHUNK - 1)/BCHUNK, NET);
  k_cast      <<<NN*DD/4/256, 256, 0, stream>>>(opf, opb);
  k_bcnt      <<<bE, 256, 0, stream>>>(ds[0],ds[1],ds[2],ds[3],ds[4], bcnt);
  k_bscan     <<<1, 256, 0, stream>>>(bcnt, bB, bC);
  k_bin2      <<<bE, 256, 0, stream>>>(ds[0],ds[1],ds[2],ds[3],ds[4],
                 sr[0],sr[1],sr[2],sr[3],sr[4], bC, bktS, bktI);
  k_deg2      <<<dim3(NB, NET), 256, 0, stream>>>(bcnt, bB, bktI, deg);
  k_chunksum  <<<dim3(CHUNKS, NET), 256, 0, stream>>>(deg, cs);
  k_scanchunks<<<NET, 64, 0, stream>>>(cs);
  k_localscan <<<dim3(CHUNKS, NET), 256, 0, stream>>>(deg, cs, cur);
  k_place2    <<<dim3(NB, NET), 256, 0, stream>>>(bcnt, bB, bktS, bktI, cur, elS, elI);
  k_gather    <<<dim3(NN/4, NET), 256, 0, stream>>>(opb,
                 ef[0],ef[1],ef[2],ef[3],ef[4],
                 cur, deg, elS, elI, A);
  k_convB     <<<(DD*KP + 255)/256, 256, 0, stream>>>(W[0],W[1],W[2],W[3],W[4],
                 bb[0],bb[1],bb[2],bb[3],bb[4], Bt);
  k_gemm      <<<(NN + 127)/128, 256, 0, stream>>>(A, Bt, opf, (float*)d_out);
}